// Round 10
// baseline (77.976 us; speedup 1.0000x reference)
//
#include <hip/hip_runtime.h>

namespace {
constexpr int C     = 128;
constexpr int T     = 64;    // token chunk
constexpr int BLK   = 512;   // 8 waves
constexpr int NWIN  = 1024;
constexpr int KVSTR = 40;    // kvs row stride
constexpr int KTSTR = 72;    // kT/vT row stride (pad: 16B-aligned rows, bank-spread)
constexpr int YNSTR = 136;   // yn / x-stage / out-stage row stride
constexpr int WSPN  = 131072;                 // shorts for pre-split weights
constexpr size_t QN = (size_t)65536 * 128;    // shorts per q/k/v plane
}

typedef __attribute__((ext_vector_type(8))) short bf16x8;
typedef __attribute__((ext_vector_type(4))) short sh4;
typedef __attribute__((ext_vector_type(4))) float f32x4;

__device__ __forceinline__ short bf16rne(float f) {
    unsigned u = __float_as_uint(f);
    u += 0x7fffu + ((u >> 16) & 1u);
    return (short)(u >> 16);
}
__device__ __forceinline__ float bf16f(short h) {
    return __uint_as_float(((unsigned)(unsigned short)h) << 16);
}
__device__ __forceinline__ void split1(float f, short& hi, short& lo) {
    hi = bf16rne(f);
    lo = bf16rne(f - bf16f(hi));
}

// Pre-split weights: [0..65535]=hi, [65536..131071]=lo; rows = wqkv(384) ++ wproj(128).
__global__ void prep_weights(const float* __restrict__ wqkv,
                             const float* __restrict__ wproj,
                             short* __restrict__ wsp) {
    const int i = blockIdx.x * 256 + threadIdx.x;
    const float f = (i < 49152) ? wqkv[i] : wproj[i - 49152];
    short hi, lo;
    split1(f, hi, lo);
    wsp[i] = hi;
    wsp[65536 + i] = lo;
}

// ============================================================================
// K1: dense qkv GEMM. 1024 blocks x 64 rows.
// Epilogue: fragments -> LDS [t][c] (pad-136) -> coalesced bf16x8 stores.
// MFMA order identical to round-9 -> bitwise-same q/k/v.
// ============================================================================
__global__ __launch_bounds__(BLK, 2)
void qkv_gemm(const float* __restrict__ x,       // [N][128]
              const short* __restrict__ wsp,     // pre-split weights
              short* __restrict__ qws,           // [N][128] bf16 (relu)
              short* __restrict__ kws,           // [N][128] bf16 (relu)
              short* __restrict__ vws)           // [N][128] bf16
{
    __shared__ __align__(16) short xh[64 * YNSTR];   // 17.4KB: x hi | out-plane staging
    __shared__ __align__(16) short xl[64 * YNSTR];   // 17.4KB: x lo

    const int tid = threadIdx.x;
    const int wv = tid >> 6, ln = tid & 63;
    const int fr = ln & 15, fg = ln >> 4;
    const int r0 = blockIdx.x * 64;

    // stage 64 rows of x, split hi/lo
#pragma unroll
    for (int it = 0; it < 2; ++it) {
        const int i = tid + it * BLK;              // < 1024
        const int t = i >> 4, c8 = (i & 15) << 3;
        const float* p = x + (size_t)(r0 + t) * C + c8;
        const float4 a = *(const float4*)p;
        const float4 b = *(const float4*)(p + 4);
        const float f[8] = {a.x, a.y, a.z, a.w, b.x, b.y, b.z, b.w};
        bf16x8 hi, lo;
#pragma unroll
        for (int u = 0; u < 8; ++u) { short h_, l_; split1(f[u], h_, l_); hi[u] = h_; lo[u] = l_; }
        *(bf16x8*)(xh + t * YNSTR + c8) = hi;
        *(bf16x8*)(xl + t * YNSTR + c8) = lo;
    }
    __syncthreads();

    // wave wv: n-tiles {3wv..3wv+2} of 24 (q 0..7, k 8..15, v 16..23), all 4 m-tiles
    f32x4 acc[3][4];
#pragma unroll
    for (int ni = 0; ni < 3; ++ni)
#pragma unroll
        for (int m = 0; m < 4; ++m) acc[ni][m] = f32x4{0.f, 0.f, 0.f, 0.f};

#pragma unroll
    for (int ksi = 0; ksi < 4; ++ksi) {
        const int koff = ksi * 32 + fg * 8;
        bf16x8 ahi[4], alo[4];
#pragma unroll
        for (int m = 0; m < 4; ++m) {
            const int row = m * 16 + fr;
            ahi[m] = *(const bf16x8*)(xh + row * YNSTR + koff);
            alo[m] = *(const bf16x8*)(xl + row * YNSTR + koff);
        }
#pragma unroll
        for (int ni = 0; ni < 3; ++ni) {
            const int idx = ((3 * wv + ni) * 16 + fr) * C + koff;
            const bf16x8 bhi = *(const bf16x8*)(wsp + idx);
            const bf16x8 blo = *(const bf16x8*)(wsp + 65536 + idx);
#pragma unroll
            for (int m = 0; m < 4; ++m) {
                acc[ni][m] = __builtin_amdgcn_mfma_f32_16x16x32_bf16(ahi[m], bhi, acc[ni][m], 0, 0, 0);
                acc[ni][m] = __builtin_amdgcn_mfma_f32_16x16x32_bf16(ahi[m], blo, acc[ni][m], 0, 0, 0);
                acc[ni][m] = __builtin_amdgcn_mfma_f32_16x16x32_bf16(alo[m], bhi, acc[ni][m], 0, 0, 0);
            }
        }
    }

    // epilogue: per plane {q,k,v}: fragments -> xh [t][c] pad-136 -> coalesced store
    const int trow = tid >> 3;                 // 0..63
    const int toff = (tid & 7) << 4;           // 0..112 step 16
#pragma unroll
    for (int p = 0; p < 3; ++p) {
        __syncthreads();                        // xh free (x-frags read / prev plane stored)
#pragma unroll
        for (int ni = 0; ni < 3; ++ni) {
            const int ti = 3 * wv + ni;
            if ((ti >> 3) == p) {
                const int lc = (ti - 8 * p) * 16 + fr;      // 0..127 within plane
                const bool rl = (p < 2);                    // relu on q and k
#pragma unroll
                for (int m = 0; m < 4; ++m)
#pragma unroll
                    for (int e = 0; e < 4; ++e) {
                        float v = acc[ni][m][e];
                        if (rl) v = fmaxf(v, 0.f);
                        xh[(m * 16 + fg * 4 + e) * YNSTR + lc] = bf16rne(v);
                    }
            }
        }
        __syncthreads();
        short* dst = (p == 0) ? qws : ((p == 1) ? kws : vws);
        const bf16x8 o0 = *(const bf16x8*)(xh + trow * YNSTR + toff);
        const bf16x8 o1 = *(const bf16x8*)(xh + trow * YNSTR + toff + 8);
        *(bf16x8*)(dst + (size_t)(r0 + trow) * C + toff) = o0;
        *(bf16x8*)(dst + (size_t)(r0 + trow) * C + toff + 8) = o1;
    }
}

// ============================================================================
// K23: per-window. stage kT/vT (transpose, no conversion) -> KV -> Y -> PROJ.
// ============================================================================
__global__ __launch_bounds__(BLK, 2)
void sla_win(const short* __restrict__ qws,
             const short* __restrict__ kws,
             const short* __restrict__ vws,
             const short* __restrict__ wsp,
             const float* __restrict__ bproj,
             const int*   __restrict__ offsets,
             float*       __restrict__ out)
{
    __shared__ __align__(16) short kT[C * KTSTR];
    __shared__ __align__(16) short vT[C * KTSTR];
    __shared__ __align__(16) short yn[T * YNSTR];
    __shared__ __align__(16) short kvs[4 * 32 * KVSTR];
    __shared__ float ss[C];

    const int win = blockIdx.x;
    const int beg = offsets[win];
    const int cnt = offsets[win + 1] - beg;
    if (cnt <= 0) return;
    const int nch = (cnt + T - 1) / T;

    const int tid = threadIdx.x;
    const int wv = tid >> 6, ln = tid & 63;
    const int fr = ln & 15, fg = ln >> 4;
    const int aH = wv >> 1, tw = wv & 1;

    f32x4 kvacc[2] = {{0.f,0.f,0.f,0.f},{0.f,0.f,0.f,0.f}};
    f32x4 sacc = {0.f, 0.f, 0.f, 0.f};
    bf16x8 ones;
#pragma unroll
    for (int u = 0; u < 8; ++u) ones[u] = (short)0x3F80;

    // ============ PASS 1: {stage-transpose | KV+s} per chunk ============
    for (int c0 = 0; c0 < nch; ++c0) {
        const int t0 = c0 * T;
        const int tc = (cnt - t0 < T) ? (cnt - t0) : T;

#pragma unroll
        for (int it = 0; it < 2; ++it) {
            const int i = tid + it * BLK;
            const int t = i >> 4, c8 = (i & 15) << 3;
            bf16x8 k8, v8;
#pragma unroll
            for (int u = 0; u < 8; ++u) { k8[u] = 0; v8[u] = 0; }
            if (t < tc) {
                k8 = *(const bf16x8*)(kws + (size_t)(beg + t0 + t) * C + c8);
                v8 = *(const bf16x8*)(vws + (size_t)(beg + t0 + t) * C + c8);
            }
#pragma unroll
            for (int u = 0; u < 8; ++u) {
                const int c = c8 + u;
                const int tt = t ^ (((c >> 3) & 7) << 3);
                kT[c * KTSTR + tt] = k8[u];
                vT[c * KTSTR + tt] = v8[u];
            }
        }
        __syncthreads();

        {   // KV: kv[aH][c][d] += kT^T v (K=64); s via ones-column MFMA
#pragma unroll
            for (int kt = 0; kt < 2; ++kt) {
                const int t8 = kt * 32 + fg * 8;
                const int cch = aH * 32 + tw * 16 + fr;
                const bf16x8 a8 = *(const bf16x8*)(kT + cch * KTSTR + (t8 ^ (((cch >> 3) & 7) << 3)));
                sacc = __builtin_amdgcn_mfma_f32_16x16x32_bf16(a8, ones, sacc, 0, 0, 0);
#pragma unroll
                for (int dt = 0; dt < 2; ++dt) {
                    const int dch = aH * 32 + dt * 16 + fr;
                    const bf16x8 b8 = *(const bf16x8*)(vT + dch * KTSTR + (t8 ^ (((dch >> 3) & 7) << 3)));
                    kvacc[dt] = __builtin_amdgcn_mfma_f32_16x16x32_bf16(a8, b8, kvacc[dt], 0, 0, 0);
                }
            }
        }
        if (c0 + 1 < nch) __syncthreads();
    }

    // KV epilogue: -> kvs[h][d][c] bf16; s -> ss
    {
#pragma unroll
        for (int dt = 0; dt < 2; ++dt) {
            const int d = dt * 16 + fr;
#pragma unroll
            for (int e = 0; e < 4; ++e) {
                const int c = tw * 16 + fg * 4 + e;
                kvs[aH * (32 * KVSTR) + d * KVSTR + c] = bf16rne(kvacc[dt][e]);
            }
        }
        if (fr == 0) {
#pragma unroll
            for (int e = 0; e < 4; ++e)
                ss[aH * 32 + tw * 16 + fg * 4 + e] = sacc[e];
        }
    }
    __syncthreads();

    // ============ PASS 2: {Y (q from global, z in-wave) | PROJ} ============
    for (int c0 = 0; c0 < nch; ++c0) {
        const int t0 = c0 * T;
        const int tc = (cnt - t0 < T) ? (cnt - t0) : T;

        {   // Y: wave (a = wv>>1 head, mp = wv&1 t-half)
            const int a = wv >> 1, mp = wv & 1;
            bf16x8 bfr[2];
#pragma unroll
            for (int dl = 0; dl < 2; ++dl)
                bfr[dl] = *(const bf16x8*)(kvs + a * (32 * KVSTR) + (dl * 16 + fr) * KVSTR + fg * 8);

            const float4 s0 = *(const float4*)(ss + a * 32 + fg * 8);
            const float4 s1 = *(const float4*)(ss + a * 32 + fg * 8 + 4);

            bf16x8 afr[2];
            float zinv[2];
#pragma unroll
            for (int mi = 0; mi < 2; ++mi) {
                const int row = (mp * 2 + mi) * 16 + fr;
                afr[mi] = *(const bf16x8*)(qws + (size_t)(beg + t0 + row) * C + a * 32 + fg * 8);
                float zp = 0.f;
                zp = fmaf(bf16f(afr[mi][0]), s0.x, zp);
                zp = fmaf(bf16f(afr[mi][1]), s0.y, zp);
                zp = fmaf(bf16f(afr[mi][2]), s0.z, zp);
                zp = fmaf(bf16f(afr[mi][3]), s0.w, zp);
                zp = fmaf(bf16f(afr[mi][4]), s1.x, zp);
                zp = fmaf(bf16f(afr[mi][5]), s1.y, zp);
                zp = fmaf(bf16f(afr[mi][6]), s1.z, zp);
                zp = fmaf(bf16f(afr[mi][7]), s1.w, zp);
                zp += __shfl_xor(zp, 16);
                zp += __shfl_xor(zp, 32);
                zinv[mi] = 1.f / (zp + 1e-6f);
            }
            f32x4 acc[2][2];
#pragma unroll
            for (int mi = 0; mi < 2; ++mi)
#pragma unroll
                for (int dl = 0; dl < 2; ++dl) {
                    acc[mi][dl] = f32x4{0.f, 0.f, 0.f, 0.f};
                    acc[mi][dl] = __builtin_amdgcn_mfma_f32_16x16x32_bf16(afr[mi], bfr[dl], acc[mi][dl], 0, 0, 0);
                }
#pragma unroll
            for (int mi = 0; mi < 2; ++mi)
#pragma unroll
                for (int e = 0; e < 4; ++e) {
                    const float zt = __shfl(zinv[mi], fg * 4 + e);
                    const int t = (mp * 2 + mi) * 16 + fg * 4 + e;
#pragma unroll
                    for (int dl = 0; dl < 2; ++dl) {
                        const int ch = a * 32 + dl * 16 + fr;
                        yn[t * YNSTR + ch] = bf16rne(acc[mi][dl][e] * zt);
                    }
                }
        }
        __syncthreads();

        {   // PROJ: wave -> ntile wv
            f32x4 acc[4];
#pragma unroll
            for (int m = 0; m < 4; ++m) acc[m] = f32x4{0.f, 0.f, 0.f, 0.f};
#pragma unroll
            for (int ksi = 0; ksi < 4; ++ksi) {
                const int koff = ksi * 32 + fg * 8;
                bf16x8 a8[4];
#pragma unroll
                for (int m = 0; m < 4; ++m) {
                    const int row = m * 16 + fr;
                    a8[m] = *(const bf16x8*)(yn + row * YNSTR + koff);
                }
                const int idx = (384 + wv * 16 + fr) * C + koff;
                const bf16x8 bhi = *(const bf16x8*)(wsp + idx);
                const bf16x8 blo = *(const bf16x8*)(wsp + 65536 + idx);
#pragma unroll
                for (int m = 0; m < 4; ++m) {
                    acc[m] = __builtin_amdgcn_mfma_f32_16x16x32_bf16(a8[m], bhi, acc[m], 0, 0, 0);
                    acc[m] = __builtin_amdgcn_mfma_f32_16x16x32_bf16(a8[m], blo, acc[m], 0, 0, 0);
                }
            }
            const int ch = wv * 16 + fr;
            const float b = bproj[ch];
#pragma unroll
            for (int m = 0; m < 4; ++m)
#pragma unroll
                for (int e = 0; e < 4; ++e) {
                    const int t = m * 16 + fg * 4 + e;
                    if (t < tc)
                        out[(size_t)(beg + t0 + t) * C + ch] = acc[m][e] + b;
                }
        }
        if (c0 + 1 < nch) __syncthreads();
    }
}

// ============================================================================
// sla6 fallback (round-8 kernel) for 17MB <= ws < 50.6MB
// ============================================================================
__global__ __launch_bounds__(BLK, 2)
void sla6(const float* __restrict__ x, const float* __restrict__ bproj,
          const int* __restrict__ offsets, const short* __restrict__ wsp,
          short* __restrict__ qws, float* __restrict__ out)
{
    __shared__ __align__(16) short xs_hi[T * C];
    __shared__ __align__(16) short xs_lo[T * C];
    __shared__ __align__(16) short kT[C * T];
    __shared__ __align__(16) short vTy[C * T];
    __shared__ __align__(16) short kvs[4 * 32 * KVSTR];
    __shared__ float ss[C];

    const int win = blockIdx.x;
    const int beg = offsets[win];
    const int cnt = offsets[win + 1] - beg;
    if (cnt <= 0) return;
    const int nch = (cnt + T - 1) / T;

    const int tid = threadIdx.x;
    const int wv = tid >> 6, ln = tid & 63;
    const int fr = ln & 15, fg = ln >> 4;

    auto loadB = [&](int row512, int koff, bf16x8& bhi, bf16x8& blo) {
        const int idx = row512 * C + koff;
        bhi = *(const bf16x8*)(wsp + idx);
        blo = *(const bf16x8*)(wsp + 65536 + idx);
    };
    auto stage = [&](int t0, int tc) {
#pragma unroll
        for (int it = 0; it < 2; ++it) {
            const int i = tid + it * BLK;
            const int t = i >> 4, c8 = (i & 15) << 3;
            float4 a = {0.f, 0.f, 0.f, 0.f}, b = {0.f, 0.f, 0.f, 0.f};
            if (t < tc) {
                const float* p = x + (size_t)(beg + t0 + t) * C + c8;
                a = *(const float4*)p;
                b = *(const float4*)(p + 4);
            }
            const float f[8] = {a.x, a.y, a.z, a.w, b.x, b.y, b.z, b.w};
            bf16x8 hi, lo;
#pragma unroll
            for (int u = 0; u < 8; ++u) { short h_, l_; split1(f[u], h_, l_); hi[u] = h_; lo[u] = l_; }
            const int s = t * C + (c8 ^ ((t & 7) << 3));
            *(bf16x8*)(xs_hi + s) = hi;
            *(bf16x8*)(xs_lo + s) = lo;
        }
    };

    const int aH = wv >> 1, tw = wv & 1;
    f32x4 kvacc[2] = {{0.f,0.f,0.f,0.f},{0.f,0.f,0.f,0.f}};
    f32x4 sacc = {0.f, 0.f, 0.f, 0.f};
    bf16x8 ones;
#pragma unroll
    for (int u = 0; u < 8; ++u) ones[u] = (short)0x3F80;

    for (int c0 = 0; c0 < nch; ++c0) {
        const int t0 = c0 * T;
        const int tc = (cnt - t0 < T) ? (cnt - t0) : T;
        stage(t0, tc);
        __syncthreads();
        sh4 qreg[4];
        {
            f32x4 acc[2][4];
#pragma unroll
            for (int ni = 0; ni < 2; ++ni)
#pragma unroll
                for (int m = 0; m < 4; ++m) acc[ni][m] = f32x4{0.f, 0.f, 0.f, 0.f};
#pragma unroll
            for (int ksi = 0; ksi < 4; ++ksi) {
                const int koff = ksi * 32 + fg * 8;
                bf16x8 ahi[4], alo[4];
#pragma unroll
                for (int m = 0; m < 4; ++m) {
                    const int row = m * 16 + fr;
                    const int s = row * C + (koff ^ ((row & 7) << 3));
                    ahi[m] = *(const bf16x8*)(xs_hi + s);
                    alo[m] = *(const bf16x8*)(xs_lo + s);
                }
#pragma unroll
                for (int ni = 0; ni < 2; ++ni) {
                    bf16x8 bhi, blo;
                    loadB(128 + (2 * wv + ni) * 16 + fr, koff, bhi, blo);
#pragma unroll
                    for (int m = 0; m < 4; ++m) {
                        acc[ni][m] = __builtin_amdgcn_mfma_f32_16x16x32_bf16(ahi[m], bhi, acc[ni][m], 0, 0, 0);
                        acc[ni][m] = __builtin_amdgcn_mfma_f32_16x16x32_bf16(ahi[m], blo, acc[ni][m], 0, 0, 0);
                        acc[ni][m] = __builtin_amdgcn_mfma_f32_16x16x32_bf16(alo[m], bhi, acc[ni][m], 0, 0, 0);
                    }
                }
            }
#pragma unroll
            for (int ni = 0; ni < 2; ++ni) {
                const int nt = 2 * wv + ni;
                const bool isk = (nt < 8);
                const int ch = (isk ? nt : nt - 8) * 16 + fr;
                short* dst = isk ? kT : vTy;
#pragma unroll
                for (int m = 0; m < 4; ++m) {
                    sh4 h4;
#pragma unroll
                    for (int e = 0; e < 4; ++e) {
                        float v = acc[ni][m][e];
                        if (isk) v = fmaxf(v, 0.f);
                        h4[e] = bf16rne(v);
                    }
                    const int tb = m * 16 + fg * 4;
                    *(sh4*)(dst + ch * T + (tb ^ ((ch & 7) << 3))) = h4;
                }
            }
        }
        {
            f32x4 acc[4];
#pragma unroll
            for (int m = 0; m < 4; ++m) acc[m] = f32x4{0.f, 0.f, 0.f, 0.f};
#pragma unroll
            for (int ksi = 0; ksi < 4; ++ksi) {
                const int koff = ksi * 32 + fg * 8;
                bf16x8 ahi[4], alo[4];
#pragma unroll
                for (int m = 0; m < 4; ++m) {
                    const int row = m * 16 + fr;
                    const int s = row * C + (koff ^ ((row & 7) << 3));
                    ahi[m] = *(const bf16x8*)(xs_hi + s);
                    alo[m] = *(const bf16x8*)(xs_lo + s);
                }
                bf16x8 bhi, blo;
                loadB(wv * 16 + fr, koff, bhi, blo);
#pragma unroll
                for (int m = 0; m < 4; ++m) {
                    acc[m] = __builtin_amdgcn_mfma_f32_16x16x32_bf16(ahi[m], bhi, acc[m], 0, 0, 0);
                    acc[m] = __builtin_amdgcn_mfma_f32_16x16x32_bf16(ahi[m], blo, acc[m], 0, 0, 0);
                    acc[m] = __builtin_amdgcn_mfma_f32_16x16x32_bf16(alo[m], bhi, acc[m], 0, 0, 0);
                }
            }
#pragma unroll
            for (int m = 0; m < 4; ++m)
#pragma unroll
                for (int e = 0; e < 4; ++e)
                    qreg[m][e] = bf16rne(fmaxf(acc[m][e], 0.f));
        }
        __syncthreads();
        {
            const int ch = wv * 16 + fr;
            if (nch == 1) {
#pragma unroll
                for (int m = 0; m < 4; ++m)
#pragma unroll
                    for (int e = 0; e < 4; ++e) {
                        const int t = m * 16 + fg * 4 + e;
                        xs_hi[t * C + (ch ^ ((t & 7) << 3))] = qreg[m][e];
                    }
            } else {
#pragma unroll
                for (int m = 0; m < 4; ++m)
#pragma unroll
                    for (int e = 0; e < 4; ++e) {
                        const int t = m * 16 + fg * 4 + e;
                        if (t < tc)
                            qws[(size_t)(beg + t0 + t) * C + ch] = qreg[m][e];
                    }
            }
        }
        {
#pragma unroll
            for (int kt = 0; kt < 2; ++kt) {
                const int t8 = kt * 32 + fg * 8;
                const int cch = aH * 32 + tw * 16 + fr;
                const bf16x8 a8 = *(const bf16x8*)(kT + cch * T + (t8 ^ ((cch & 7) << 3)));
                sacc = __builtin_amdgcn_mfma_f32_16x16x32_bf16(a8, ones, sacc, 0, 0, 0);
#pragma unroll
                for (int dt = 0; dt < 2; ++dt) {
                    const int dch = aH * 32 + dt * 16 + fr;
                    const bf16x8 b8 = *(const bf16x8*)(vTy + dch * T + (t8 ^ ((dch & 7) << 3)));
                    kvacc[dt] = __builtin_amdgcn_mfma_f32_16x16x32_bf16(a8, b8, kvacc[dt], 0, 0, 0);
                }
            }
        }
        if (c0 + 1 < nch) __syncthreads();
    }
    {
#pragma unroll
        for (int dt = 0; dt < 2; ++dt) {
            const int d = dt * 16 + fr;
#pragma unroll
            for (int e = 0; e < 4; ++e) {
                const int c = tw * 16 + fg * 4 + e;
                kvs[aH * (32 * KVSTR) + d * KVSTR + c] = bf16rne(kvacc[dt][e]);
            }
        }
        if (fr == 0) {
#pragma unroll
            for (int e = 0; e < 4; ++e)
                ss[aH * 32 + tw * 16 + fg * 4 + e] = sacc[e];
        }
    }
    __syncthreads();
    for (int c0 = 0; c0 < nch; ++c0) {
        const int t0 = c0 * T;
        const int tc = (cnt - t0 < T) ? (cnt - t0) : T;
        {
            const int a = wv >> 1, mp = wv & 1;
            bf16x8 bfr[2];
#pragma unroll
            for (int dl = 0; dl < 2; ++dl)
                bfr[dl] = *(const bf16x8*)(kvs + a * (32 * KVSTR) + (dl * 16 + fr) * KVSTR + fg * 8);
            const float4 s0 = *(const float4*)(ss + a * 32 + fg * 8);
            const float4 s1 = *(const float4*)(ss + a * 32 + fg * 8 + 4);
            bf16x8 afr[2];
            float zinv[2];
#pragma unroll
            for (int mi = 0; mi < 2; ++mi) {
                const int row = (mp * 2 + mi) * 16 + fr;
                if (nch == 1)
                    afr[mi] = *(const bf16x8*)(xs_hi + row * C + ((a * 32 + fg * 8) ^ ((row & 7) << 3)));
                else
                    afr[mi] = *(const bf16x8*)(qws + (size_t)(beg + t0 + row) * C + a * 32 + fg * 8);
                float zp = 0.f;
                zp = fmaf(bf16f(afr[mi][0]), s0.x, zp);
                zp = fmaf(bf16f(afr[mi][1]), s0.y, zp);
                zp = fmaf(bf16f(afr[mi][2]), s0.z, zp);
                zp = fmaf(bf16f(afr[mi][3]), s0.w, zp);
                zp = fmaf(bf16f(afr[mi][4]), s1.x, zp);
                zp = fmaf(bf16f(afr[mi][5]), s1.y, zp);
                zp = fmaf(bf16f(afr[mi][6]), s1.z, zp);
                zp = fmaf(bf16f(afr[mi][7]), s1.w, zp);
                zp += __shfl_xor(zp, 16);
                zp += __shfl_xor(zp, 32);
                zinv[mi] = 1.f / (zp + 1e-6f);
            }
            f32x4 acc[2][2];
#pragma unroll
            for (int mi = 0; mi < 2; ++mi)
#pragma unroll
                for (int dl = 0; dl < 2; ++dl) {
                    acc[mi][dl] = f32x4{0.f, 0.f, 0.f, 0.f};
                    acc[mi][dl] = __builtin_amdgcn_mfma_f32_16x16x32_bf16(afr[mi], bfr[dl], acc[mi][dl], 0, 0, 0);
                }
#pragma unroll
            for (int mi = 0; mi < 2; ++mi)
#pragma unroll
                for (int e = 0; e < 4; ++e) {
                    const float zt = __shfl(zinv[mi], fg * 4 + e);
                    const int t = (mp * 2 + mi) * 16 + fg * 4 + e;
#pragma unroll
                    for (int dl = 0; dl < 2; ++dl) {
                        const int ch = a * 32 + dl * 16 + fr;
                        vTy[t * C + (ch ^ ((t & 7) << 3))] = bf16rne(acc[mi][dl][e] * zt);
                    }
                }
        }
        __syncthreads();
        {
            f32x4 acc[4];
#pragma unroll
            for (int m = 0; m < 4; ++m) acc[m] = f32x4{0.f, 0.f, 0.f, 0.f};
#pragma unroll
            for (int ksi = 0; ksi < 4; ++ksi) {
                const int koff = ksi * 32 + fg * 8;
                bf16x8 a8[4];
#pragma unroll
                for (int m = 0; m < 4; ++m) {
                    const int row = m * 16 + fr;
                    a8[m] = *(const bf16x8*)(vTy + row * C + (koff ^ ((row & 7) << 3)));
                }
                bf16x8 bhi, blo;
                loadB(384 + wv * 16 + fr, koff, bhi, blo);
#pragma unroll
                for (int m = 0; m < 4; ++m) {
                    acc[m] = __builtin_amdgcn_mfma_f32_16x16x32_bf16(a8[m], bhi, acc[m], 0, 0, 0);
                    acc[m] = __builtin_amdgcn_mfma_f32_16x16x32_bf16(a8[m], blo, acc[m], 0, 0, 0);
                }
            }
            const int ch = wv * 16 + fr;
            const float b = bproj[ch];
#pragma unroll
            for (int m = 0; m < 4; ++m)
#pragma unroll
                for (int e = 0; e < 4; ++e) {
                    const int t = m * 16 + fg * 4 + e;
                    if (t < tc)
                        out[(size_t)(beg + t0 + t) * C + ch] = acc[m][e] + b;
                }
        }
        if (c0 + 1 < nch) __syncthreads();
    }
}

extern "C" void kernel_launch(void* const* d_in, const int* in_sizes, int n_in,
                              void* d_out, int out_size, void* d_ws, size_t ws_size,
                              hipStream_t stream)
{
    const float* x       = (const float*)d_in[0];
    const float* wqkv    = (const float*)d_in[1];
    const float* wproj   = (const float*)d_in[2];
    const float* bproj   = (const float*)d_in[3];
    const int*   offsets = (const int*)d_in[5];
    float* out = (float*)d_out;
    short* wsp = (short*)d_ws;

    const size_t need_split = ((size_t)WSPN + 3 * QN) * sizeof(short);
    const size_t need_sla6  = ((size_t)WSPN + QN) * sizeof(short);

    if (ws_size >= need_split) {
        short* qws = wsp + WSPN;
        short* kws = qws + QN;
        short* vws = kws + QN;
        hipLaunchKernelGGL(prep_weights, dim3(256), dim3(256), 0, stream, wqkv, wproj, wsp);
        hipLaunchKernelGGL(qkv_gemm, dim3(65536 / 64), dim3(BLK), 0, stream,
                           x, wsp, qws, kws, vws);
        hipLaunchKernelGGL(sla_win, dim3(NWIN), dim3(BLK), 0, stream,
                           qws, kws, vws, wsp, bproj, offsets, out);
    } else if (ws_size >= need_sla6) {
        hipLaunchKernelGGL(prep_weights, dim3(256), dim3(256), 0, stream, wqkv, wproj, wsp);
        hipLaunchKernelGGL(sla6, dim3(NWIN), dim3(BLK), 0, stream,
                           x, bproj, offsets, wsp, wsp + WSPN, out);
    }
}

// Round 11
// 71.638 us; speedup vs baseline: 1.0885x; 1.0885x over previous
//
#include <hip/hip_runtime.h>

namespace {
constexpr int C     = 128;
constexpr int T     = 64;    // token chunk
constexpr int BLK   = 512;   // 8 waves
constexpr int NWIN  = 1024;
constexpr int KVSTR = 40;    // kvs row stride
constexpr int KTSTR = 72;    // kT/vT row stride (pad: 16B-aligned rows, bank-spread)
constexpr int YNSTR = 136;   // yn / x-stage / out-stage row stride
constexpr int WSPN  = 131072;                 // shorts for pre-split weights
constexpr size_t QN = (size_t)65536 * 128;    // shorts per q/k/v plane
}

typedef __attribute__((ext_vector_type(8))) short bf16x8;
typedef __attribute__((ext_vector_type(4))) short sh4;
typedef __attribute__((ext_vector_type(4))) float f32x4;

__device__ __forceinline__ short bf16rne(float f) {
    unsigned u = __float_as_uint(f);
    u += 0x7fffu + ((u >> 16) & 1u);
    return (short)(u >> 16);
}
__device__ __forceinline__ float bf16f(short h) {
    return __uint_as_float(((unsigned)(unsigned short)h) << 16);
}
__device__ __forceinline__ void split1(float f, short& hi, short& lo) {
    hi = bf16rne(f);
    lo = bf16rne(f - bf16f(hi));
}

// Pre-split weights: [0..65535]=hi, [65536..131071]=lo; rows = wqkv(384) ++ wproj(128).
__global__ void prep_weights(const float* __restrict__ wqkv,
                             const float* __restrict__ wproj,
                             short* __restrict__ wsp) {
    const int i = blockIdx.x * 256 + threadIdx.x;
    const float f = (i < 49152) ? wqkv[i] : wproj[i - 49152];
    short hi, lo;
    split1(f, hi, lo);
    wsp[i] = hi;
    wsp[65536 + i] = lo;
}

// ============================================================================
// K1: dense qkv GEMM. 256 blocks x 256 rows (4 chunks of 64).
// B-fragments hoisted into registers ONCE per block (24 x bf16x8 pairs/wave);
// K-loop is pure LDS+MFMA. Epilogue: LDS-coalesced, q->xh || k->xl then v->xh.
// Per-row MFMA order identical to round-10 -> bitwise-same q/k/v.
// ============================================================================
__global__ __launch_bounds__(BLK, 2)
void qkv_gemm(const float* __restrict__ x,       // [N][128]
              const short* __restrict__ wsp,     // pre-split weights
              short* __restrict__ qws,           // [N][128] bf16 (relu)
              short* __restrict__ kws,           // [N][128] bf16 (relu)
              short* __restrict__ vws)           // [N][128] bf16
{
    __shared__ __align__(16) short xh[64 * YNSTR];   // 17.4KB: x hi | q / v staging
    __shared__ __align__(16) short xl[64 * YNSTR];   // 17.4KB: x lo | k staging

    const int tid = threadIdx.x;
    const int wv = tid >> 6, ln = tid & 63;
    const int fr = ln & 15, fg = ln >> 4;
    const int r0 = blockIdx.x * 256;

    // ---- hoist all B fragments for this wave's 3 ntiles (issued up front) ----
    bf16x8 Bh[3][4], Bl[3][4];
#pragma unroll
    for (int ni = 0; ni < 3; ++ni)
#pragma unroll
        for (int ksi = 0; ksi < 4; ++ksi) {
            const int idx = ((3 * wv + ni) * 16 + fr) * C + ksi * 32 + fg * 8;
            Bh[ni][ksi] = *(const bf16x8*)(wsp + idx);
            Bl[ni][ksi] = *(const bf16x8*)(wsp + 65536 + idx);
        }

    const int trow = tid >> 3;                 // 0..63
    const int toff = (tid & 7) << 4;           // 0..112 step 16

    for (int ch = 0; ch < 4; ++ch) {
        const int rbase = r0 + ch * 64;
        if (ch) __syncthreads();                // prev epilogue reads done

        // ---- stage 64 rows of x, split hi/lo ----
#pragma unroll
        for (int it = 0; it < 2; ++it) {
            const int i = tid + it * BLK;
            const int t = i >> 4, c8 = (i & 15) << 3;
            const float* p = x + (size_t)(rbase + t) * C + c8;
            const float4 a = *(const float4*)p;
            const float4 b = *(const float4*)(p + 4);
            const float f[8] = {a.x, a.y, a.z, a.w, b.x, b.y, b.z, b.w};
            bf16x8 hi, lo;
#pragma unroll
            for (int u = 0; u < 8; ++u) { short h_, l_; split1(f[u], h_, l_); hi[u] = h_; lo[u] = l_; }
            *(bf16x8*)(xh + t * YNSTR + c8) = hi;
            *(bf16x8*)(xl + t * YNSTR + c8) = lo;
        }
        __syncthreads();

        // ---- K-loop: pure LDS + MFMA (B cached in registers) ----
        f32x4 acc[3][4];
#pragma unroll
        for (int ni = 0; ni < 3; ++ni)
#pragma unroll
            for (int m = 0; m < 4; ++m) acc[ni][m] = f32x4{0.f, 0.f, 0.f, 0.f};

#pragma unroll
        for (int ksi = 0; ksi < 4; ++ksi) {
            const int koff = ksi * 32 + fg * 8;
            bf16x8 ahi[4], alo[4];
#pragma unroll
            for (int m = 0; m < 4; ++m) {
                const int row = m * 16 + fr;
                ahi[m] = *(const bf16x8*)(xh + row * YNSTR + koff);
                alo[m] = *(const bf16x8*)(xl + row * YNSTR + koff);
            }
#pragma unroll
            for (int ni = 0; ni < 3; ++ni)
#pragma unroll
                for (int m = 0; m < 4; ++m) {
                    acc[ni][m] = __builtin_amdgcn_mfma_f32_16x16x32_bf16(ahi[m], Bh[ni][ksi], acc[ni][m], 0, 0, 0);
                    acc[ni][m] = __builtin_amdgcn_mfma_f32_16x16x32_bf16(ahi[m], Bl[ni][ksi], acc[ni][m], 0, 0, 0);
                    acc[ni][m] = __builtin_amdgcn_mfma_f32_16x16x32_bf16(alo[m], Bh[ni][ksi], acc[ni][m], 0, 0, 0);
                }
        }
        __syncthreads();                        // xh/xl reads done -> reuse as staging

        // ---- epilogue phase A: q -> xh, k -> xl ----
#pragma unroll
        for (int ni = 0; ni < 3; ++ni) {
            const int ti = 3 * wv + ni;
            const int p = ti >> 3;
            if (p < 2) {
                short* buf = (p == 0) ? xh : xl;
                const int lc = (ti & 7) * 16 + fr;
#pragma unroll
                for (int m = 0; m < 4; ++m)
#pragma unroll
                    for (int e = 0; e < 4; ++e)
                        buf[(m * 16 + fg * 4 + e) * YNSTR + lc] =
                            bf16rne(fmaxf(acc[ni][m][e], 0.f));
            }
        }
        __syncthreads();
        {
            const bf16x8 q0 = *(const bf16x8*)(xh + trow * YNSTR + toff);
            const bf16x8 q1 = *(const bf16x8*)(xh + trow * YNSTR + toff + 8);
            const bf16x8 k0 = *(const bf16x8*)(xl + trow * YNSTR + toff);
            const bf16x8 k1 = *(const bf16x8*)(xl + trow * YNSTR + toff + 8);
            *(bf16x8*)(qws + (size_t)(rbase + trow) * C + toff)     = q0;
            *(bf16x8*)(qws + (size_t)(rbase + trow) * C + toff + 8) = q1;
            *(bf16x8*)(kws + (size_t)(rbase + trow) * C + toff)     = k0;
            *(bf16x8*)(kws + (size_t)(rbase + trow) * C + toff + 8) = k1;
        }
        __syncthreads();

        // ---- epilogue phase B: v -> xh ----
#pragma unroll
        for (int ni = 0; ni < 3; ++ni) {
            const int ti = 3 * wv + ni;
            if ((ti >> 3) == 2) {
                const int lc = (ti & 7) * 16 + fr;
#pragma unroll
                for (int m = 0; m < 4; ++m)
#pragma unroll
                    for (int e = 0; e < 4; ++e)
                        xh[(m * 16 + fg * 4 + e) * YNSTR + lc] = bf16rne(acc[ni][m][e]);
            }
        }
        __syncthreads();
        {
            const bf16x8 v0 = *(const bf16x8*)(xh + trow * YNSTR + toff);
            const bf16x8 v1 = *(const bf16x8*)(xh + trow * YNSTR + toff + 8);
            *(bf16x8*)(vws + (size_t)(rbase + trow) * C + toff)     = v0;
            *(bf16x8*)(vws + (size_t)(rbase + trow) * C + toff + 8) = v1;
        }
    }
}

// ============================================================================
// K23: per-window. stage kT/vT (transpose, no conversion) -> KV -> Y -> PROJ.
// ============================================================================
__global__ __launch_bounds__(BLK, 2)
void sla_win(const short* __restrict__ qws,
             const short* __restrict__ kws,
             const short* __restrict__ vws,
             const short* __restrict__ wsp,
             const float* __restrict__ bproj,
             const int*   __restrict__ offsets,
             float*       __restrict__ out)
{
    __shared__ __align__(16) short kT[C * KTSTR];
    __shared__ __align__(16) short vT[C * KTSTR];
    __shared__ __align__(16) short yn[T * YNSTR];
    __shared__ __align__(16) short kvs[4 * 32 * KVSTR];
    __shared__ float ss[C];

    const int win = blockIdx.x;
    const int beg = offsets[win];
    const int cnt = offsets[win + 1] - beg;
    if (cnt <= 0) return;
    const int nch = (cnt + T - 1) / T;

    const int tid = threadIdx.x;
    const int wv = tid >> 6, ln = tid & 63;
    const int fr = ln & 15, fg = ln >> 4;
    const int aH = wv >> 1, tw = wv & 1;

    f32x4 kvacc[2] = {{0.f,0.f,0.f,0.f},{0.f,0.f,0.f,0.f}};
    f32x4 sacc = {0.f, 0.f, 0.f, 0.f};
    bf16x8 ones;
#pragma unroll
    for (int u = 0; u < 8; ++u) ones[u] = (short)0x3F80;

    // ============ PASS 1: {stage-transpose | KV+s} per chunk ============
    for (int c0 = 0; c0 < nch; ++c0) {
        const int t0 = c0 * T;
        const int tc = (cnt - t0 < T) ? (cnt - t0) : T;

#pragma unroll
        for (int it = 0; it < 2; ++it) {
            const int i = tid + it * BLK;
            const int t = i >> 4, c8 = (i & 15) << 3;
            bf16x8 k8, v8;
#pragma unroll
            for (int u = 0; u < 8; ++u) { k8[u] = 0; v8[u] = 0; }
            if (t < tc) {
                k8 = *(const bf16x8*)(kws + (size_t)(beg + t0 + t) * C + c8);
                v8 = *(const bf16x8*)(vws + (size_t)(beg + t0 + t) * C + c8);
            }
#pragma unroll
            for (int u = 0; u < 8; ++u) {
                const int c = c8 + u;
                const int tt = t ^ (((c >> 3) & 7) << 3);
                kT[c * KTSTR + tt] = k8[u];
                vT[c * KTSTR + tt] = v8[u];
            }
        }
        __syncthreads();

        {   // KV: kv[aH][c][d] += kT^T v (K=64); s via ones-column MFMA
#pragma unroll
            for (int kt = 0; kt < 2; ++kt) {
                const int t8 = kt * 32 + fg * 8;
                const int cch = aH * 32 + tw * 16 + fr;
                const bf16x8 a8 = *(const bf16x8*)(kT + cch * KTSTR + (t8 ^ (((cch >> 3) & 7) << 3)));
                sacc = __builtin_amdgcn_mfma_f32_16x16x32_bf16(a8, ones, sacc, 0, 0, 0);
#pragma unroll
                for (int dt = 0; dt < 2; ++dt) {
                    const int dch = aH * 32 + dt * 16 + fr;
                    const bf16x8 b8 = *(const bf16x8*)(vT + dch * KTSTR + (t8 ^ (((dch >> 3) & 7) << 3)));
                    kvacc[dt] = __builtin_amdgcn_mfma_f32_16x16x32_bf16(a8, b8, kvacc[dt], 0, 0, 0);
                }
            }
        }
        if (c0 + 1 < nch) __syncthreads();
    }

    // KV epilogue: -> kvs[h][d][c] bf16; s -> ss
    {
#pragma unroll
        for (int dt = 0; dt < 2; ++dt) {
            const int d = dt * 16 + fr;
#pragma unroll
            for (int e = 0; e < 4; ++e) {
                const int c = tw * 16 + fg * 4 + e;
                kvs[aH * (32 * KVSTR) + d * KVSTR + c] = bf16rne(kvacc[dt][e]);
            }
        }
        if (fr == 0) {
#pragma unroll
            for (int e = 0; e < 4; ++e)
                ss[aH * 32 + tw * 16 + fg * 4 + e] = sacc[e];
        }
    }
    __syncthreads();

    // ============ PASS 2: {Y (q from global, z in-wave) | PROJ} ============
    for (int c0 = 0; c0 < nch; ++c0) {
        const int t0 = c0 * T;
        const int tc = (cnt - t0 < T) ? (cnt - t0) : T;

        {   // Y: wave (a = wv>>1 head, mp = wv&1 t-half)
            const int a = wv >> 1, mp = wv & 1;
            bf16x8 bfr[2];
#pragma unroll
            for (int dl = 0; dl < 2; ++dl)
                bfr[dl] = *(const bf16x8*)(kvs + a * (32 * KVSTR) + (dl * 16 + fr) * KVSTR + fg * 8);

            const float4 s0 = *(const float4*)(ss + a * 32 + fg * 8);
            const float4 s1 = *(const float4*)(ss + a * 32 + fg * 8 + 4);

            bf16x8 afr[2];
            float zinv[2];
#pragma unroll
            for (int mi = 0; mi < 2; ++mi) {
                const int row = (mp * 2 + mi) * 16 + fr;
                afr[mi] = *(const bf16x8*)(qws + (size_t)(beg + t0 + row) * C + a * 32 + fg * 8);
                float zp = 0.f;
                zp = fmaf(bf16f(afr[mi][0]), s0.x, zp);
                zp = fmaf(bf16f(afr[mi][1]), s0.y, zp);
                zp = fmaf(bf16f(afr[mi][2]), s0.z, zp);
                zp = fmaf(bf16f(afr[mi][3]), s0.w, zp);
                zp = fmaf(bf16f(afr[mi][4]), s1.x, zp);
                zp = fmaf(bf16f(afr[mi][5]), s1.y, zp);
                zp = fmaf(bf16f(afr[mi][6]), s1.z, zp);
                zp = fmaf(bf16f(afr[mi][7]), s1.w, zp);
                zp += __shfl_xor(zp, 16);
                zp += __shfl_xor(zp, 32);
                zinv[mi] = 1.f / (zp + 1e-6f);
            }
            f32x4 acc[2][2];
#pragma unroll
            for (int mi = 0; mi < 2; ++mi)
#pragma unroll
                for (int dl = 0; dl < 2; ++dl) {
                    acc[mi][dl] = f32x4{0.f, 0.f, 0.f, 0.f};
                    acc[mi][dl] = __builtin_amdgcn_mfma_f32_16x16x32_bf16(afr[mi], bfr[dl], acc[mi][dl], 0, 0, 0);
                }
#pragma unroll
            for (int mi = 0; mi < 2; ++mi)
#pragma unroll
                for (int e = 0; e < 4; ++e) {
                    const float zt = __shfl(zinv[mi], fg * 4 + e);
                    const int t = (mp * 2 + mi) * 16 + fg * 4 + e;
#pragma unroll
                    for (int dl = 0; dl < 2; ++dl) {
                        const int ch = a * 32 + dl * 16 + fr;
                        yn[t * YNSTR + ch] = bf16rne(acc[mi][dl][e] * zt);
                    }
                }
        }
        __syncthreads();

        {   // PROJ: wave -> ntile wv
            f32x4 acc[4];
#pragma unroll
            for (int m = 0; m < 4; ++m) acc[m] = f32x4{0.f, 0.f, 0.f, 0.f};
#pragma unroll
            for (int ksi = 0; ksi < 4; ++ksi) {
                const int koff = ksi * 32 + fg * 8;
                bf16x8 a8[4];
#pragma unroll
                for (int m = 0; m < 4; ++m) {
                    const int row = m * 16 + fr;
                    a8[m] = *(const bf16x8*)(yn + row * YNSTR + koff);
                }
                const int idx = (384 + wv * 16 + fr) * C + koff;
                const bf16x8 bhi = *(const bf16x8*)(wsp + idx);
                const bf16x8 blo = *(const bf16x8*)(wsp + 65536 + idx);
#pragma unroll
                for (int m = 0; m < 4; ++m) {
                    acc[m] = __builtin_amdgcn_mfma_f32_16x16x32_bf16(a8[m], bhi, acc[m], 0, 0, 0);
                    acc[m] = __builtin_amdgcn_mfma_f32_16x16x32_bf16(a8[m], blo, acc[m], 0, 0, 0);
                }
            }
            const int ch = wv * 16 + fr;
            const float b = bproj[ch];
#pragma unroll
            for (int m = 0; m < 4; ++m)
#pragma unroll
                for (int e = 0; e < 4; ++e) {
                    const int t = m * 16 + fg * 4 + e;
                    if (t < tc)
                        out[(size_t)(beg + t0 + t) * C + ch] = acc[m][e] + b;
                }
        }
        if (c0 + 1 < nch) __syncthreads();
    }
}

// ============================================================================
// sla6 fallback (round-8 kernel) for 17MB <= ws < 50.6MB
// ============================================================================
__global__ __launch_bounds__(BLK, 2)
void sla6(const float* __restrict__ x, const float* __restrict__ bproj,
          const int* __restrict__ offsets, const short* __restrict__ wsp,
          short* __restrict__ qws, float* __restrict__ out)
{
    __shared__ __align__(16) short xs_hi[T * C];
    __shared__ __align__(16) short xs_lo[T * C];
    __shared__ __align__(16) short kT[C * T];
    __shared__ __align__(16) short vTy[C * T];
    __shared__ __align__(16) short kvs[4 * 32 * KVSTR];
    __shared__ float ss[C];

    const int win = blockIdx.x;
    const int beg = offsets[win];
    const int cnt = offsets[win + 1] - beg;
    if (cnt <= 0) return;
    const int nch = (cnt + T - 1) / T;

    const int tid = threadIdx.x;
    const int wv = tid >> 6, ln = tid & 63;
    const int fr = ln & 15, fg = ln >> 4;

    auto loadB = [&](int row512, int koff, bf16x8& bhi, bf16x8& blo) {
        const int idx = row512 * C + koff;
        bhi = *(const bf16x8*)(wsp + idx);
        blo = *(const bf16x8*)(wsp + 65536 + idx);
    };
    auto stage = [&](int t0, int tc) {
#pragma unroll
        for (int it = 0; it < 2; ++it) {
            const int i = tid + it * BLK;
            const int t = i >> 4, c8 = (i & 15) << 3;
            float4 a = {0.f, 0.f, 0.f, 0.f}, b = {0.f, 0.f, 0.f, 0.f};
            if (t < tc) {
                const float* p = x + (size_t)(beg + t0 + t) * C + c8;
                a = *(const float4*)p;
                b = *(const float4*)(p + 4);
            }
            const float f[8] = {a.x, a.y, a.z, a.w, b.x, b.y, b.z, b.w};
            bf16x8 hi, lo;
#pragma unroll
            for (int u = 0; u < 8; ++u) { short h_, l_; split1(f[u], h_, l_); hi[u] = h_; lo[u] = l_; }
            const int s = t * C + (c8 ^ ((t & 7) << 3));
            *(bf16x8*)(xs_hi + s) = hi;
            *(bf16x8*)(xs_lo + s) = lo;
        }
    };

    const int aH = wv >> 1, tw = wv & 1;
    f32x4 kvacc[2] = {{0.f,0.f,0.f,0.f},{0.f,0.f,0.f,0.f}};
    f32x4 sacc = {0.f, 0.f, 0.f, 0.f};
    bf16x8 ones;
#pragma unroll
    for (int u = 0; u < 8; ++u) ones[u] = (short)0x3F80;

    for (int c0 = 0; c0 < nch; ++c0) {
        const int t0 = c0 * T;
        const int tc = (cnt - t0 < T) ? (cnt - t0) : T;
        stage(t0, tc);
        __syncthreads();
        sh4 qreg[4];
        {
            f32x4 acc[2][4];
#pragma unroll
            for (int ni = 0; ni < 2; ++ni)
#pragma unroll
                for (int m = 0; m < 4; ++m) acc[ni][m] = f32x4{0.f, 0.f, 0.f, 0.f};
#pragma unroll
            for (int ksi = 0; ksi < 4; ++ksi) {
                const int koff = ksi * 32 + fg * 8;
                bf16x8 ahi[4], alo[4];
#pragma unroll
                for (int m = 0; m < 4; ++m) {
                    const int row = m * 16 + fr;
                    const int s = row * C + (koff ^ ((row & 7) << 3));
                    ahi[m] = *(const bf16x8*)(xs_hi + s);
                    alo[m] = *(const bf16x8*)(xs_lo + s);
                }
#pragma unroll
                for (int ni = 0; ni < 2; ++ni) {
                    bf16x8 bhi, blo;
                    loadB(128 + (2 * wv + ni) * 16 + fr, koff, bhi, blo);
#pragma unroll
                    for (int m = 0; m < 4; ++m) {
                        acc[ni][m] = __builtin_amdgcn_mfma_f32_16x16x32_bf16(ahi[m], bhi, acc[ni][m], 0, 0, 0);
                        acc[ni][m] = __builtin_amdgcn_mfma_f32_16x16x32_bf16(ahi[m], blo, acc[ni][m], 0, 0, 0);
                        acc[ni][m] = __builtin_amdgcn_mfma_f32_16x16x32_bf16(alo[m], bhi, acc[ni][m], 0, 0, 0);
                    }
                }
            }
#pragma unroll
            for (int ni = 0; ni < 2; ++ni) {
                const int nt = 2 * wv + ni;
                const bool isk = (nt < 8);
                const int ch = (isk ? nt : nt - 8) * 16 + fr;
                short* dst = isk ? kT : vTy;
#pragma unroll
                for (int m = 0; m < 4; ++m) {
                    sh4 h4;
#pragma unroll
                    for (int e = 0; e < 4; ++e) {
                        float v = acc[ni][m][e];
                        if (isk) v = fmaxf(v, 0.f);
                        h4[e] = bf16rne(v);
                    }
                    const int tb = m * 16 + fg * 4;
                    *(sh4*)(dst + ch * T + (tb ^ ((ch & 7) << 3))) = h4;
                }
            }
        }
        {
            f32x4 acc[4];
#pragma unroll
            for (int m = 0; m < 4; ++m) acc[m] = f32x4{0.f, 0.f, 0.f, 0.f};
#pragma unroll
            for (int ksi = 0; ksi < 4; ++ksi) {
                const int koff = ksi * 32 + fg * 8;
                bf16x8 ahi[4], alo[4];
#pragma unroll
                for (int m = 0; m < 4; ++m) {
                    const int row = m * 16 + fr;
                    const int s = row * C + (koff ^ ((row & 7) << 3));
                    ahi[m] = *(const bf16x8*)(xs_hi + s);
                    alo[m] = *(const bf16x8*)(xs_lo + s);
                }
                bf16x8 bhi, blo;
                loadB(wv * 16 + fr, koff, bhi, blo);
#pragma unroll
                for (int m = 0; m < 4; ++m) {
                    acc[m] = __builtin_amdgcn_mfma_f32_16x16x32_bf16(ahi[m], bhi, acc[m], 0, 0, 0);
                    acc[m] = __builtin_amdgcn_mfma_f32_16x16x32_bf16(ahi[m], blo, acc[m], 0, 0, 0);
                    acc[m] = __builtin_amdgcn_mfma_f32_16x16x32_bf16(alo[m], bhi, acc[m], 0, 0, 0);
                }
            }
#pragma unroll
            for (int m = 0; m < 4; ++m)
#pragma unroll
                for (int e = 0; e < 4; ++e)
                    qreg[m][e] = bf16rne(fmaxf(acc[m][e], 0.f));
        }
        __syncthreads();
        {
            const int ch = wv * 16 + fr;
            if (nch == 1) {
#pragma unroll
                for (int m = 0; m < 4; ++m)
#pragma unroll
                    for (int e = 0; e < 4; ++e) {
                        const int t = m * 16 + fg * 4 + e;
                        xs_hi[t * C + (ch ^ ((t & 7) << 3))] = qreg[m][e];
                    }
            } else {
#pragma unroll
                for (int m = 0; m < 4; ++m)
#pragma unroll
                    for (int e = 0; e < 4; ++e) {
                        const int t = m * 16 + fg * 4 + e;
                        if (t < tc)
                            qws[(size_t)(beg + t0 + t) * C + ch] = qreg[m][e];
                    }
            }
        }
        {
#pragma unroll
            for (int kt = 0; kt < 2; ++kt) {
                const int t8 = kt * 32 + fg * 8;
                const int cch = aH * 32 + tw * 16 + fr;
                const bf16x8 a8 = *(const bf16x8*)(kT + cch * T + (t8 ^ ((cch & 7) << 3)));
                sacc = __builtin_amdgcn_mfma_f32_16x16x32_bf16(a8, ones, sacc, 0, 0, 0);
#pragma unroll
                for (int dt = 0; dt < 2; ++dt) {
                    const int dch = aH * 32 + dt * 16 + fr;
                    const bf16x8 b8 = *(const bf16x8*)(vTy + dch * T + (t8 ^ ((dch & 7) << 3)));
                    kvacc[dt] = __builtin_amdgcn_mfma_f32_16x16x32_bf16(a8, b8, kvacc[dt], 0, 0, 0);
                }
            }
        }
        if (c0 + 1 < nch) __syncthreads();
    }
    {
#pragma unroll
        for (int dt = 0; dt < 2; ++dt) {
            const int d = dt * 16 + fr;
#pragma unroll
            for (int e = 0; e < 4; ++e) {
                const int c = tw * 16 + fg * 4 + e;
                kvs[aH * (32 * KVSTR) + d * KVSTR + c] = bf16rne(kvacc[dt][e]);
            }
        }
        if (fr == 0) {
#pragma unroll
            for (int e = 0; e < 4; ++e)
                ss[aH * 32 + tw * 16 + fg * 4 + e] = sacc[e];
        }
    }
    __syncthreads();
    for (int c0 = 0; c0 < nch; ++c0) {
        const int t0 = c0 * T;
        const int tc = (cnt - t0 < T) ? (cnt - t0) : T;
        {
            const int a = wv >> 1, mp = wv & 1;
            bf16x8 bfr[2];
#pragma unroll
            for (int dl = 0; dl < 2; ++dl)
                bfr[dl] = *(const bf16x8*)(kvs + a * (32 * KVSTR) + (dl * 16 + fr) * KVSTR + fg * 8);
            const float4 s0 = *(const float4*)(ss + a * 32 + fg * 8);
            const float4 s1 = *(const float4*)(ss + a * 32 + fg * 8 + 4);
            bf16x8 afr[2];
            float zinv[2];
#pragma unroll
            for (int mi = 0; mi < 2; ++mi) {
                const int row = (mp * 2 + mi) * 16 + fr;
                if (nch == 1)
                    afr[mi] = *(const bf16x8*)(xs_hi + row * C + ((a * 32 + fg * 8) ^ ((row & 7) << 3)));
                else
                    afr[mi] = *(const bf16x8*)(qws + (size_t)(beg + t0 + row) * C + a * 32 + fg * 8);
                float zp = 0.f;
                zp = fmaf(bf16f(afr[mi][0]), s0.x, zp);
                zp = fmaf(bf16f(afr[mi][1]), s0.y, zp);
                zp = fmaf(bf16f(afr[mi][2]), s0.z, zp);
                zp = fmaf(bf16f(afr[mi][3]), s0.w, zp);
                zp = fmaf(bf16f(afr[mi][4]), s1.x, zp);
                zp = fmaf(bf16f(afr[mi][5]), s1.y, zp);
                zp = fmaf(bf16f(afr[mi][6]), s1.z, zp);
                zp = fmaf(bf16f(afr[mi][7]), s1.w, zp);
                zp += __shfl_xor(zp, 16);
                zp += __shfl_xor(zp, 32);
                zinv[mi] = 1.f / (zp + 1e-6f);
            }
            f32x4 acc[2][2];
#pragma unroll
            for (int mi = 0; mi < 2; ++mi)
#pragma unroll
                for (int dl = 0; dl < 2; ++dl) {
                    acc[mi][dl] = f32x4{0.f, 0.f, 0.f, 0.f};
                    acc[mi][dl] = __builtin_amdgcn_mfma_f32_16x16x32_bf16(afr[mi], bfr[dl], acc[mi][dl], 0, 0, 0);
                }
#pragma unroll
            for (int mi = 0; mi < 2; ++mi)
#pragma unroll
                for (int e = 0; e < 4; ++e) {
                    const float zt = __shfl(zinv[mi], fg * 4 + e);
                    const int t = (mp * 2 + mi) * 16 + fg * 4 + e;
#pragma unroll
                    for (int dl = 0; dl < 2; ++dl) {
                        const int ch = a * 32 + dl * 16 + fr;
                        vTy[t * C + (ch ^ ((t & 7) << 3))] = bf16rne(acc[mi][dl][e] * zt);
                    }
                }
        }
        __syncthreads();
        {
            f32x4 acc[4];
#pragma unroll
            for (int m = 0; m < 4; ++m) acc[m] = f32x4{0.f, 0.f, 0.f, 0.f};
#pragma unroll
            for (int ksi = 0; ksi < 4; ++ksi) {
                const int koff = ksi * 32 + fg * 8;
                bf16x8 a8[4];
#pragma unroll
                for (int m = 0; m < 4; ++m) {
                    const int row = m * 16 + fr;
                    a8[m] = *(const bf16x8*)(vTy + row * C + (koff ^ ((row & 7) << 3)));
                }
                bf16x8 bhi, blo;
                loadB(384 + wv * 16 + fr, koff, bhi, blo);
#pragma unroll
                for (int m = 0; m < 4; ++m) {
                    acc[m] = __builtin_amdgcn_mfma_f32_16x16x32_bf16(a8[m], bhi, acc[m], 0, 0, 0);
                    acc[m] = __builtin_amdgcn_mfma_f32_16x16x32_bf16(a8[m], blo, acc[m], 0, 0, 0);
                }
            }
            const int ch = wv * 16 + fr;
            const float b = bproj[ch];
#pragma unroll
            for (int m = 0; m < 4; ++m)
#pragma unroll
                for (int e = 0; e < 4; ++e) {
                    const int t = m * 16 + fg * 4 + e;
                    if (t < tc)
                        out[(size_t)(beg + t0 + t) * C + ch] = acc[m][e] + b;
                }
        }
        if (c0 + 1 < nch) __syncthreads();
    }
}

extern "C" void kernel_launch(void* const* d_in, const int* in_sizes, int n_in,
                              void* d_out, int out_size, void* d_ws, size_t ws_size,
                              hipStream_t stream)
{
    const float* x       = (const float*)d_in[0];
    const float* wqkv    = (const float*)d_in[1];
    const float* wproj   = (const float*)d_in[2];
    const float* bproj   = (const float*)d_in[3];
    const int*   offsets = (const int*)d_in[5];
    float* out = (float*)d_out;
    short* wsp = (short*)d_ws;

    const size_t need_split = ((size_t)WSPN + 3 * QN) * sizeof(short);
    const size_t need_sla6  = ((size_t)WSPN + QN) * sizeof(short);

    if (ws_size >= need_split) {
        short* qws = wsp + WSPN;
        short* kws = qws + QN;
        short* vws = kws + QN;
        hipLaunchKernelGGL(prep_weights, dim3(256), dim3(256), 0, stream, wqkv, wproj, wsp);
        hipLaunchKernelGGL(qkv_gemm, dim3(65536 / 256), dim3(BLK), 0, stream,
                           x, wsp, qws, kws, vws);
        hipLaunchKernelGGL(sla_win, dim3(NWIN), dim3(BLK), 0, stream,
                           qws, kws, vws, wsp, bproj, offsets, out);
    } else if (ws_size >= need_sla6) {
        hipLaunchKernelGGL(prep_weights, dim3(256), dim3(256), 0, stream, wqkv, wproj, wsp);
        hipLaunchKernelGGL(sla6, dim3(NWIN), dim3(BLK), 0, stream,
                           x, bproj, offsets, wsp, wsp + WSPN, out);
    }
}